// Round 4
// baseline (18.085 us; speedup 1.0000x reference)
//
#include <hip/hip_runtime.h>
#include <hip/hip_bf16.h>

// RandomForest: out = mean_t(x @ W[t] + b[t]) = x @ mean_t(W) + mean_t(b)
// x: [65536,128] f32, W: [64,128,32] f32, b: [64,32] f32, out: [65536,32] f32
//
// prep: W_avg -> bf16 hi/lo MFMA B-fragments + b_avg f32 (in d_ws).
// gemm: LDS-free, barrier-free. A-fragments built directly in registers from
// coalesced float4 loads of x; 3-product compensated bf16 MFMA
// (Ah*Bh + Ah*Bl + Al*Bh). Verified fragment mappings from round 2/3.

#define T_ 64
#define F_ 128
#define C_ 32
#define B_ 65536

typedef short short8 __attribute__((ext_vector_type(8)));   // 8 bf16 = 4 VGPR
typedef float f32x4 __attribute__((ext_vector_type(4)));

__device__ __forceinline__ unsigned short bf16_rne(float f) {
    union { float f; unsigned int u; } v; v.f = f;
    unsigned int r = (v.u + 0x7FFFu + ((v.u >> 16) & 1u)) >> 16;
    return (unsigned short)r;
}
__device__ __forceinline__ float bf16_tof(unsigned short h) {
    union { unsigned int u; float f; } v; v.u = ((unsigned int)h) << 16;
    return v.f;
}

// ws byte layout:
//   [0     .. 8191 ]  B_hi frags: ((nt*4+ks)*64 + lane)*16 + j*2   (ushort bf16)
//   [8192  .. 16383]  B_lo frags, same indexing
//   [16384 .. 16511]  b_avg f32[32]

// ---------------- kernel 1: average W,b -> bf16 hi/lo B-fragments ------------
__global__ __launch_bounds__(256) void prep_kernel(const float* __restrict__ W,
                                                   const float* __restrict__ bv,
                                                   unsigned char* __restrict__ ws) {
    __shared__ float red[256];
    const int t = threadIdx.x;
    const int o = t & 63;
    const int q = t >> 6;
    const int gid = blockIdx.x * 64 + o;          // 0..4095  (f = gid>>5, c = gid&31)
    float s = 0.f;
#pragma unroll
    for (int i = 0; i < 16; ++i) s += W[(q * 16 + i) * (F_ * C_) + gid];
    red[t] = s;
    __syncthreads();
    if (q == 0) {
        float a = (s + red[o + 64] + red[o + 128] + red[o + 192]) * (1.0f / T_);
        unsigned short hi = bf16_rne(a);
        unsigned short lo = bf16_rne(a - bf16_tof(hi));
        int f = gid >> 5, c = gid & 31;
        // B[k=f][n=c] -> frag(nt,ks), lane = 16*g + (c&15), reg j ; k' = 8g + j
        int nt = c >> 4, ks = f >> 5, g = (f >> 3) & 3, j = f & 7;
        unsigned int off = (unsigned int)((nt * 4 + ks) * 64 + (g * 16 + (c & 15))) * 16u
                         + (unsigned int)j * 2u;
        *(unsigned short*)(ws + off) = hi;
        *(unsigned short*)(ws + 8192 + off) = lo;
    }
    if (blockIdx.x == 0 && t < C_) {
        float s2 = 0.f;
#pragma unroll
        for (int tt = 0; tt < T_; ++tt) s2 += bv[tt * C_ + t];
        *(float*)(ws + 16384 + t * 4) = s2 * (1.0f / T_);
    }
}

// ---------------- kernel 2: out = x @ W_avg + b_avg via MFMA -----------------
// 1024 blocks x 256 threads (4 independent waves, 16 rows each). No LDS, no
// barrier. 12 waves/CU (launch_bounds 3/EU -> VGPR cap ~170, est use ~150).
#define GBLK 256

__device__ __forceinline__ void cvt_hilo(const float4 a, const float4 b,
                                         short8* hi8, short8* lo8) {
    float f[8] = {a.x, a.y, a.z, a.w, b.x, b.y, b.z, b.w};
    unsigned short h[8], l[8];
#pragma unroll
    for (int i = 0; i < 8; ++i) {
        __hip_bfloat16 hb = __float2bfloat16(f[i]);          // RNE, fuses to cvt_pk
        h[i] = __bfloat16_as_ushort(hb);
        float back = __bfloat162float(hb);
        l[i] = __bfloat16_as_ushort(__float2bfloat16(f[i] - back));
    }
    union { unsigned int u[4]; short8 s; } H, L;
#pragma unroll
    for (int j = 0; j < 4; ++j) {
        H.u[j] = (unsigned int)h[2 * j] | ((unsigned int)h[2 * j + 1] << 16);
        L.u[j] = (unsigned int)l[2 * j] | ((unsigned int)l[2 * j + 1] << 16);
    }
    *hi8 = H.s; *lo8 = L.s;
}

__global__ __launch_bounds__(GBLK, 3) void forest_mfma(const float* __restrict__ x,
                                                       const unsigned char* __restrict__ ws,
                                                       float* __restrict__ out) {
    const int t   = threadIdx.x;
    const int l   = t & 63;
    const int wid = blockIdx.x * (GBLK / 64) + (t >> 6);   // 0..4095
    const int row0 = wid * 16;
    const int r = l & 15;          // A row offset; also C/D col
    const int g = l >> 4;          // k-group / C/D row group

    // 1) x loads directly in A-fragment order: lane holds
    //    x[row0+r][32*ks + 8*g + {0..7}]  ->  2 float4 per ks. HBM critical path.
    const float* xr = x + (size_t)(row0 + r) * F_ + g * 8;
    float4 xa[4], xb[4];
#pragma unroll
    for (int ks = 0; ks < 4; ++ks) {
        xa[ks] = *(const float4*)(xr + ks * 32);
        xb[ks] = *(const float4*)(xr + ks * 32 + 4);
    }

    // 2) B fragments (L2-hot broadcast; perfectly coalesced 1 KB/instr)
    const uint4* Bq = (const uint4*)ws;           // 512 hi frag-quads, then 512 lo
    uint4 bhv[2][4], blv[2][4];
#pragma unroll
    for (int nt = 0; nt < 2; ++nt)
#pragma unroll
        for (int ks = 0; ks < 4; ++ks) {
            bhv[nt][ks] = Bq[(nt * 4 + ks) * 64 + l];
            blv[nt][ks] = Bq[512 + (nt * 4 + ks) * 64 + l];
        }
    const float* bias = (const float*)(ws + 16384);
    const float b0 = bias[r], b1 = bias[16 + r];

    // 3) convert fp32 -> bf16 hi/lo A-fragments in registers (no LDS)
    short8 ah[4], al[4];
#pragma unroll
    for (int ks = 0; ks < 4; ++ks) cvt_hilo(xa[ks], xb[ks], &ah[ks], &al[ks]);

    // 4) 24 MFMAs: 2 N-tiles x 4 K-steps x 3 compensated products
    f32x4 acc0 = {b0, b0, b0, b0};
    f32x4 acc1 = {b1, b1, b1, b1};
#pragma unroll
    for (int ks = 0; ks < 4; ++ks) {
        short8 bh0 = *(short8*)&bhv[0][ks], bl0 = *(short8*)&blv[0][ks];
        short8 bh1 = *(short8*)&bhv[1][ks], bl1 = *(short8*)&blv[1][ks];
        acc0 = __builtin_amdgcn_mfma_f32_16x16x32_bf16(ah[ks], bh0, acc0, 0, 0, 0);
        acc0 = __builtin_amdgcn_mfma_f32_16x16x32_bf16(ah[ks], bl0, acc0, 0, 0, 0);
        acc0 = __builtin_amdgcn_mfma_f32_16x16x32_bf16(al[ks], bh0, acc0, 0, 0, 0);
        acc1 = __builtin_amdgcn_mfma_f32_16x16x32_bf16(ah[ks], bh1, acc1, 0, 0, 0);
        acc1 = __builtin_amdgcn_mfma_f32_16x16x32_bf16(ah[ks], bl1, acc1, 0, 0, 0);
        acc1 = __builtin_amdgcn_mfma_f32_16x16x32_bf16(al[ks], bh1, acc1, 0, 0, 0);
    }

    // 5) epilogue: C/D layout (m89-verified): col = lane&15, row = 4*(lane>>4)+rr
    const int orow = row0 + 4 * g;
#pragma unroll
    for (int rr = 0; rr < 4; ++rr) {
        out[(size_t)(orow + rr) * C_ + r]      = acc0[rr];
        out[(size_t)(orow + rr) * C_ + 16 + r] = acc1[rr];
    }
}

extern "C" void kernel_launch(void* const* d_in, const int* in_sizes, int n_in,
                              void* d_out, int out_size, void* d_ws, size_t ws_size,
                              hipStream_t stream) {
    const float* x = (const float*)d_in[0];   // logits [65536,128]
    const float* W = (const float*)d_in[1];   // [64,128,32]
    const float* b = (const float*)d_in[2];   // [64,32]
    float* out = (float*)d_out;               // [65536,32]
    unsigned char* ws = (unsigned char*)d_ws; // uses 16.5 KB

    prep_kernel<<<64, 256, 0, stream>>>(W, b, ws);
    forest_mfma<<<B_ / 64, GBLK, 0, stream>>>(x, ws, out);
}